// Round 1
// baseline (734.347 us; speedup 1.0000x reference)
//
#include <hip/hip_runtime.h>

#define NN 50000
#define NE 1600000
#define D 64
#define NR 6

__global__ void zero_i32_k(int* __restrict__ p, int n) {
    int i = blockIdx.x * blockDim.x + threadIdx.x;
    if (i < n) p[i] = 0;
}

__global__ void count_edges_k(const int* __restrict__ dst, const int* __restrict__ et,
                              int* __restrict__ cnt) {
    int e = blockIdx.x * blockDim.x + threadIdx.x;
    if (e < NE) atomicAdd(&cnt[dst[e] * NR + et[e]], 1);
}

__global__ void make_norm_k(const int* __restrict__ cnt, float* __restrict__ norm, int n) {
    int i = blockIdx.x * blockDim.x + threadIdx.x;
    if (i < n) {
        int c = cnt[i];
        norm[i] = (c > 0) ? 1.0f / (float)c : 0.0f;
    }
}

// xr[r, n, o] = sum_d x[n, d] * W[r, d, o]; one wave per (r, n), lane = o
__global__ void compute_xr_k(const float* __restrict__ x, const float* __restrict__ W,
                             float* __restrict__ xr) {
    int t = blockIdx.x * blockDim.x + threadIdx.x;
    int pair = t >> 6;   // r * NN + n
    int o = t & 63;
    if (pair >= NR * NN) return;
    int r = pair / NN;
    int n = pair - r * NN;
    const float* xrow = x + n * D;
    const float* Wr = W + r * D * D + o;
    float acc = 0.0f;
#pragma unroll
    for (int d = 0; d < D; ++d) acc = fmaf(xrow[d], Wr[d * D], acc);
    xr[pair * D + o] = acc;
}

// out[n, o] = bias[o] + sum_d x[n, d] * root[d, o]
__global__ void init_out_k(const float* __restrict__ x, const float* __restrict__ root,
                           const float* __restrict__ bias, float* __restrict__ out) {
    int t = blockIdx.x * blockDim.x + threadIdx.x;
    int n = t >> 6;
    int o = t & 63;
    if (n >= NN) return;
    const float* xrow = x + n * D;
    float acc = bias[o];
#pragma unroll
    for (int d = 0; d < D; ++d) acc = fmaf(xrow[d], root[d * D + o], acc);
    out[t] = acc;
}

// one wave per edge, lane = channel
__global__ void scatter_k(const int* __restrict__ srcs, const int* __restrict__ dsts,
                          const int* __restrict__ et, const float* __restrict__ xr,
                          const float* __restrict__ norm, float* __restrict__ out) {
    int t = blockIdx.x * blockDim.x + threadIdx.x;
    int e = t >> 6;
    int o = t & 63;
    if (e >= NE) return;
    int s = srcs[e];
    int d2 = dsts[e];
    int r = et[e];
    float nrm = norm[d2 * NR + r];
    float v = xr[((size_t)r * NN + (size_t)s) * D + o] * nrm;
    atomicAdd(&out[d2 * D + o], v);
}

// fallback (small ws): per-edge on-the-fly matvec
__global__ void scatter_mv_k(const int* __restrict__ srcs, const int* __restrict__ dsts,
                             const int* __restrict__ et, const float* __restrict__ x,
                             const float* __restrict__ W, const float* __restrict__ norm,
                             float* __restrict__ out) {
    int t = blockIdx.x * blockDim.x + threadIdx.x;
    int e = t >> 6;
    int o = t & 63;
    if (e >= NE) return;
    int s = srcs[e];
    int d2 = dsts[e];
    int r = et[e];
    float nrm = norm[d2 * NR + r];
    const float* xrow = x + s * D;
    const float* Wr = W + r * D * D + o;
    float acc = 0.0f;
#pragma unroll
    for (int d = 0; d < D; ++d) acc = fmaf(xrow[d], Wr[d * D], acc);
    atomicAdd(&out[d2 * D + o], acc * nrm);
}

extern "C" void kernel_launch(void* const* d_in, const int* in_sizes, int n_in,
                              void* d_out, int out_size, void* d_ws, size_t ws_size,
                              hipStream_t stream) {
    const float* x    = (const float*)d_in[0];
    const float* W    = (const float*)d_in[1];
    const float* root = (const float*)d_in[2];
    const float* bias = (const float*)d_in[3];
    const int*   ei   = (const int*)d_in[4];   // [2, NE]
    const int*   et   = (const int*)d_in[5];   // [NE]
    float* out = (float*)d_out;

    const int* srcs = ei;
    const int* dsts = ei + NE;

    // workspace layout
    const int nseg = NN * NR;                       // 300000
    char* ws = (char*)d_ws;
    int*   cnt  = (int*)ws;                         // nseg ints
    float* norm = (float*)(ws + (size_t)nseg * 4);  // nseg floats
    float* xr   = (float*)(ws + (size_t)nseg * 8);  // NR*NN*D floats (76.8 MB)
    size_t need_xr = (size_t)nseg * 8 + (size_t)NR * NN * D * 4;
    bool have_xr = ws_size >= need_xr;

    // 1. counts
    zero_i32_k<<<(nseg + 255) / 256, 256, 0, stream>>>(cnt, nseg);
    count_edges_k<<<(NE + 255) / 256, 256, 0, stream>>>(dsts, et, cnt);
    make_norm_k<<<(nseg + 255) / 256, 256, 0, stream>>>(cnt, norm, nseg);

    // 2. xr = einsum('nd,rdo->rno')
    if (have_xr) {
        int pairs = NR * NN;
        compute_xr_k<<<((size_t)pairs * 64 + 255) / 256, 256, 0, stream>>>(x, W, xr);
    }

    // 3. out = bias + x @ root
    init_out_k<<<((size_t)NN * 64 + 255) / 256, 256, 0, stream>>>(x, root, bias, out);

    // 4. scatter messages
    if (have_xr) {
        scatter_k<<<((size_t)NE * 64 + 255) / 256, 256, 0, stream>>>(srcs, dsts, et, xr, norm, out);
    } else {
        scatter_mv_k<<<((size_t)NE * 64 + 255) / 256, 256, 0, stream>>>(srcs, dsts, et, x, W, norm, out);
    }
}

// Round 2
// 460.736 us; speedup vs baseline: 1.5939x; 1.5939x over previous
//
#include <hip/hip_runtime.h>

#define NN 50000
#define NE 1600000
#define D 64
#define NR 6
#define NSEG (NN * NR)
#define SCAN_B 256
#define SCAN_NB ((NN + SCAN_B - 1) / SCAN_B)   // 196

__global__ void zero_i32_k(int* __restrict__ p, int n) {
    int i = blockIdx.x * blockDim.x + threadIdx.x;
    if (i < n) p[i] = 0;
}

__global__ void count_edges_k(const int* __restrict__ dst, const int* __restrict__ et,
                              int* __restrict__ cnt) {
    int e = blockIdx.x * blockDim.x + threadIdx.x;
    if (e < NE) atomicAdd(&cnt[dst[e] * NR + et[e]], 1);
}

// per node: norm for each relation + total degree
__global__ void norm_deg_k(const int* __restrict__ cnt, float* __restrict__ norm,
                           int* __restrict__ deg) {
    int n = blockIdx.x * blockDim.x + threadIdx.x;
    if (n >= NN) return;
    int s = 0;
#pragma unroll
    for (int r = 0; r < NR; ++r) {
        int c = cnt[n * NR + r];
        s += c;
        norm[n * NR + r] = (c > 0) ? 1.0f / (float)c : 0.0f;
    }
    deg[n] = s;
}

// two-level exclusive scan over deg[NN] -> rowstart[NN+1], cursor[NN]
__global__ void scanA_k(const int* __restrict__ deg, int* __restrict__ incl,
                        int* __restrict__ blocksum) {
    __shared__ int s[SCAN_B];
    int t = threadIdx.x, i = blockIdx.x * SCAN_B + t;
    s[t] = (i < NN) ? deg[i] : 0;
    __syncthreads();
    for (int off = 1; off < SCAN_B; off <<= 1) {
        int u = (t >= off) ? s[t - off] : 0;
        __syncthreads();
        s[t] += u;
        __syncthreads();
    }
    if (i < NN) incl[i] = s[t];
    if (t == SCAN_B - 1) blocksum[blockIdx.x] = s[t];
}

__global__ void scanB_k(const int* __restrict__ blocksum, int* __restrict__ blockoff) {
    __shared__ int s[SCAN_B];
    int t = threadIdx.x;
    s[t] = (t < SCAN_NB) ? blocksum[t] : 0;
    __syncthreads();
    for (int off = 1; off < SCAN_B; off <<= 1) {
        int u = (t >= off) ? s[t - off] : 0;
        __syncthreads();
        s[t] += u;
        __syncthreads();
    }
    if (t < SCAN_NB) blockoff[t] = s[t];   // inclusive block sums
}

__global__ void scanC_k(const int* __restrict__ incl, const int* __restrict__ blockoff,
                        int* __restrict__ rowstart, int* __restrict__ cursor) {
    int i = blockIdx.x * blockDim.x + threadIdx.x;
    if (i >= NN) return;
    int b = i >> 8;
    int Ri = incl[i] + (b > 0 ? blockoff[b - 1] : 0);
    rowstart[i + 1] = Ri;
    int prev;
    if (i == 0) { prev = 0; rowstart[0] = 0; }
    else {
        int b2 = (i - 1) >> 8;
        prev = incl[i - 1] + (b2 > 0 ? blockoff[b2 - 1] : 0);
    }
    cursor[i] = prev;
}

// bucket edges by dst; payload = {xr row index, norm as bits}
__global__ void build_pay_k(const int* __restrict__ srcs, const int* __restrict__ dsts,
                            const int* __restrict__ et, const float* __restrict__ norm,
                            int* __restrict__ cursor, int2* __restrict__ pay) {
    int e = blockIdx.x * blockDim.x + threadIdx.x;
    if (e >= NE) return;
    int d2 = dsts[e], r = et[e];
    int pos = atomicAdd(&cursor[d2], 1);
    pay[pos] = make_int2(r * NN + srcs[e], __float_as_int(norm[d2 * NR + r]));
}

// xr[r,n,o] = sum_d x[n,d]*W[r,d,o]; W_r column held in 64 VGPRs, grid-stride nodes
__global__ __launch_bounds__(256) void compute_xr2_k(const float* __restrict__ x,
                                                     const float* __restrict__ W,
                                                     float* __restrict__ xr) {
    int r = blockIdx.y;
    int wid = (blockIdx.x * blockDim.x + threadIdx.x) >> 6;
    int o = threadIdx.x & 63;
    int nwaves = (gridDim.x * blockDim.x) >> 6;
    float wcol[D];
    const float* Wr = W + r * D * D;
#pragma unroll
    for (int d = 0; d < D; ++d) wcol[d] = Wr[d * D + o];
    for (int n = wid; n < NN; n += nwaves) {
        const float4* xrow = (const float4*)(x + n * D);
        float acc = 0.0f;
#pragma unroll
        for (int q = 0; q < D / 4; ++q) {
            float4 xa = xrow[q];
            acc = fmaf(xa.x, wcol[4 * q + 0], acc);
            acc = fmaf(xa.y, wcol[4 * q + 1], acc);
            acc = fmaf(xa.z, wcol[4 * q + 2], acc);
            acc = fmaf(xa.w, wcol[4 * q + 3], acc);
        }
        xr[((size_t)r * NN + n) * D + o] = acc;
    }
}

// one wave per node: out[n,:] = bias + x[n]@root + sum_edges norm * xr[row,:]
__global__ __launch_bounds__(256) void gather_k(const float* __restrict__ x,
                                                const float* __restrict__ root,
                                                const float* __restrict__ bias,
                                                const int* __restrict__ rowstart,
                                                const int2* __restrict__ pay,
                                                const float* __restrict__ xr,
                                                float* __restrict__ out) {
    int n = (blockIdx.x * blockDim.x + threadIdx.x) >> 6;
    int o = threadIdx.x & 63;
    if (n >= NN) return;
    float acc = bias[o];
    const float4* xrow = (const float4*)(x + n * D);
#pragma unroll
    for (int q = 0; q < D / 4; ++q) {
        float4 xa = xrow[q];
        acc = fmaf(xa.x, root[(4 * q + 0) * D + o], acc);
        acc = fmaf(xa.y, root[(4 * q + 1) * D + o], acc);
        acc = fmaf(xa.z, root[(4 * q + 2) * D + o], acc);
        acc = fmaf(xa.w, root[(4 * q + 3) * D + o], acc);
    }
    int k0 = rowstart[n], k1 = rowstart[n + 1];
    int k = k0;
    int2 p = (k < k1) ? pay[k] : make_int2(0, 0);
    while (k < k1) {
        int2 cur = p;
        if (k + 1 < k1) p = pay[k + 1];
        acc = fmaf(__int_as_float(cur.y), xr[(size_t)cur.x * D + o], acc);
        ++k;
    }
    out[n * D + o] = acc;
}

// ---------- fallback path (small ws): round-1 atomic scatter ----------
__global__ void init_out_k(const float* __restrict__ x, const float* __restrict__ root,
                           const float* __restrict__ bias, float* __restrict__ out) {
    int t = blockIdx.x * blockDim.x + threadIdx.x;
    int n = t >> 6;
    int o = t & 63;
    if (n >= NN) return;
    const float* xrow = x + n * D;
    float acc = bias[o];
#pragma unroll
    for (int d = 0; d < D; ++d) acc = fmaf(xrow[d], root[d * D + o], acc);
    out[t] = acc;
}

__global__ void scatter_mv_k(const int* __restrict__ srcs, const int* __restrict__ dsts,
                             const int* __restrict__ et, const float* __restrict__ x,
                             const float* __restrict__ W, const float* __restrict__ norm,
                             float* __restrict__ out) {
    int t = blockIdx.x * blockDim.x + threadIdx.x;
    int e = t >> 6;
    int o = t & 63;
    if (e >= NE) return;
    int s = srcs[e];
    int d2 = dsts[e];
    int r = et[e];
    float nrm = norm[d2 * NR + r];
    const float* xrow = x + s * D;
    const float* Wr = W + r * D * D + o;
    float acc = 0.0f;
#pragma unroll
    for (int d = 0; d < D; ++d) acc = fmaf(xrow[d], Wr[d * D], acc);
    atomicAdd(&out[d2 * D + o], acc * nrm);
}

extern "C" void kernel_launch(void* const* d_in, const int* in_sizes, int n_in,
                              void* d_out, int out_size, void* d_ws, size_t ws_size,
                              hipStream_t stream) {
    const float* x    = (const float*)d_in[0];
    const float* W    = (const float*)d_in[1];
    const float* root = (const float*)d_in[2];
    const float* bias = (const float*)d_in[3];
    const int*   ei   = (const int*)d_in[4];
    const int*   et   = (const int*)d_in[5];
    float* out = (float*)d_out;
    const int* srcs = ei;
    const int* dsts = ei + NE;

    char* ws = (char*)d_ws;
    size_t off = 0;
    int*   cnt      = (int*)(ws + off); off += (size_t)NSEG * 4;
    float* norm     = (float*)(ws + off); off += (size_t)NSEG * 4;
    int*   deg      = (int*)(ws + off); off += (size_t)NN * 4;
    int*   incl     = (int*)(ws + off); off += (size_t)NN * 4;
    int*   blocksum = (int*)(ws + off); off += (size_t)SCAN_NB * 4;
    int*   blockoff = (int*)(ws + off); off += (size_t)SCAN_NB * 4;
    int*   rowstart = (int*)(ws + off); off += (size_t)(NN + 1) * 4;
    int*   cursor   = (int*)(ws + off); off += (size_t)NN * 4;
    off = (off + 7) & ~(size_t)7;
    int2*  pay      = (int2*)(ws + off); off += (size_t)NE * 8;
    float* xr       = (float*)(ws + off); off += (size_t)NR * NN * D * 4;
    bool big = ws_size >= off;

    // counts + norms (shared by both paths)
    zero_i32_k<<<(NSEG + 255) / 256, 256, 0, stream>>>(cnt, NSEG);
    count_edges_k<<<(NE + 255) / 256, 256, 0, stream>>>(dsts, et, cnt);

    if (big) {
        norm_deg_k<<<(NN + 255) / 256, 256, 0, stream>>>(cnt, norm, deg);
        scanA_k<<<SCAN_NB, SCAN_B, 0, stream>>>(deg, incl, blocksum);
        scanB_k<<<1, SCAN_B, 0, stream>>>(blocksum, blockoff);
        scanC_k<<<(NN + 255) / 256, 256, 0, stream>>>(incl, blockoff, rowstart, cursor);
        build_pay_k<<<(NE + 255) / 256, 256, 0, stream>>>(srcs, dsts, et, norm, cursor, pay);
        compute_xr2_k<<<dim3(256, NR), 256, 0, stream>>>(x, W, xr);
        gather_k<<<((size_t)NN * 64 + 255) / 256, 256, 0, stream>>>(x, root, bias, rowstart, pay, xr, out);
    } else {
        norm_deg_k<<<(NN + 255) / 256, 256, 0, stream>>>(cnt, norm, (int*)cnt /*unused-safe*/);
        init_out_k<<<((size_t)NN * 64 + 255) / 256, 256, 0, stream>>>(x, root, bias, out);
        scatter_mv_k<<<((size_t)NE * 64 + 255) / 256, 256, 0, stream>>>(srcs, dsts, et, x, W, norm, out);
    }
}